// Round 1
// baseline (3765.512 us; speedup 1.0000x reference)
//
#include <hip/hip_runtime.h>
#include <math.h>

// Problem constants
#define B_    8
#define S_    4096
#define T_    77
#define C_    1280
#define CENC_ 2048
#define H_    20
#define D_    64
#define HD_   1280
#define M1_   (B_*S_)     // 32768 rows for Q / O GEMMs
#define MKV_  (B_*T_)     // 616 rows for K/V GEMM
#define KTOK_ 12          // ceil(77*0.15)
#define KPOS_ 1229        // ceil(4096*0.3)
#define SCALE_ 0.125f     // 1/sqrt(64)
#define CMIX_  0.15f      // STRENGTH*(1-ALPHA)
#define CINJ_  (0.25f/7.0f) // FIW*STRENGTH/(B-1)

// ---------------------------------------------------------------------------
// fp32 GEMM, 128x128 tile, BK=16, 256 threads, 8x8 micro-tile per thread.
// M = 32768, N = 1280 fixed; K is a parameter. Optional fused prologue
// (position-mask injection on A) and epilogue (bias + residual) for the
// output projection.
// ---------------------------------------------------------------------------
template<bool INJECT, bool FUSE_OUT>
__global__ __launch_bounds__(256)
void gemm128_kernel(const float* __restrict__ A, const float* __restrict__ Bm,
                    float* __restrict__ Cout, int K,
                    const float* __restrict__ posm, const float* __restrict__ csum,
                    const float* __restrict__ bias, const float* __restrict__ resid)
{
    __shared__ float As[16][128];   // transposed: As[k][m]
    __shared__ float Bs[16][128];   // Bs[k][n]
    const int tid = threadIdx.x;
    const int n0 = blockIdx.x * 128;
    const int m0 = blockIdx.y * 128;
    const int tx = tid & 15, ty = tid >> 4;
    const int ar = tid >> 2;          // 0..63 (A row within tile; also +64)
    const int ak = (tid & 3) << 2;    // 0,4,8,12 (A k-offset)
    const int bk = tid >> 5;          // 0..7 (B k-row; also +8)
    const int bn = (tid & 31) << 2;   // 0..124 (B col offset)
    const int N = 1280;

    float acc[8][8] = {};

    const float* Ap0 = A + (size_t)(m0 + ar) * K + ak;
    const float* Ap1 = Ap0 + (size_t)64 * K;
    const float* Bp0 = Bm + (size_t)bk * N + n0 + bn;
    const float* Bp1 = Bp0 + (size_t)8 * N;

    float inj_am0 = 1.f, inj_cf0 = 0.f, inj_am1 = 1.f, inj_cf1 = 0.f;
    const float* cs0 = nullptr; const float* cs1 = nullptr;
    if constexpr (INJECT) {
        const float mv0 = posm[m0 + ar];
        const float mv1 = posm[m0 + ar + 64];
        inj_cf0 = mv0 * CINJ_; inj_am0 = 1.0f - 8.0f * inj_cf0;
        inj_cf1 = mv1 * CINJ_; inj_am1 = 1.0f - 8.0f * inj_cf1;
        cs0 = csum + (size_t)((m0 + ar) & (S_ - 1)) * HD_ + ak;
        cs1 = csum + (size_t)((m0 + ar + 64) & (S_ - 1)) * HD_ + ak;
    }

    for (int k0 = 0; k0 < K; k0 += 16) {
        float4 a0 = *(const float4*)(Ap0 + k0);
        float4 a1 = *(const float4*)(Ap1 + k0);
        const float4 b0 = *(const float4*)(Bp0 + (size_t)k0 * N);
        const float4 b1 = *(const float4*)(Bp1 + (size_t)k0 * N);
        if constexpr (INJECT) {
            const float4 c0 = *(const float4*)(cs0 + k0);
            const float4 c1 = *(const float4*)(cs1 + k0);
            a0.x = a0.x * inj_am0 + inj_cf0 * c0.x;
            a0.y = a0.y * inj_am0 + inj_cf0 * c0.y;
            a0.z = a0.z * inj_am0 + inj_cf0 * c0.z;
            a0.w = a0.w * inj_am0 + inj_cf0 * c0.w;
            a1.x = a1.x * inj_am1 + inj_cf1 * c1.x;
            a1.y = a1.y * inj_am1 + inj_cf1 * c1.y;
            a1.z = a1.z * inj_am1 + inj_cf1 * c1.z;
            a1.w = a1.w * inj_am1 + inj_cf1 * c1.w;
        }
        __syncthreads();
        As[ak+0][ar] = a0.x; As[ak+1][ar] = a0.y; As[ak+2][ar] = a0.z; As[ak+3][ar] = a0.w;
        As[ak+0][ar+64] = a1.x; As[ak+1][ar+64] = a1.y; As[ak+2][ar+64] = a1.z; As[ak+3][ar+64] = a1.w;
        *(float4*)&Bs[bk][bn] = b0;
        *(float4*)&Bs[bk+8][bn] = b1;
        __syncthreads();
        #pragma unroll
        for (int kk = 0; kk < 16; ++kk) {
            const float4 av0 = *(const float4*)&As[kk][ty*4];
            const float4 av1 = *(const float4*)&As[kk][ty*4 + 64];
            const float4 bv0 = *(const float4*)&Bs[kk][tx*4];
            const float4 bv1 = *(const float4*)&Bs[kk][tx*4 + 64];
            const float arr[8] = {av0.x,av0.y,av0.z,av0.w,av1.x,av1.y,av1.z,av1.w};
            const float brr[8] = {bv0.x,bv0.y,bv0.z,bv0.w,bv1.x,bv1.y,bv1.z,bv1.w};
            #pragma unroll
            for (int r = 0; r < 8; ++r)
                #pragma unroll
                for (int c = 0; c < 8; ++c)
                    acc[r][c] = fmaf(arr[r], brr[c], acc[r][c]);
        }
    }

    float4 bb[2];
    if constexpr (FUSE_OUT) {
        bb[0] = *(const float4*)(bias + n0 + tx*4);
        bb[1] = *(const float4*)(bias + n0 + 64 + tx*4);
    }
    #pragma unroll
    for (int r = 0; r < 8; ++r) {
        const int row = m0 + (r >> 2) * 64 + ty * 4 + (r & 3);
        #pragma unroll
        for (int cg = 0; cg < 2; ++cg) {
            const int col = n0 + cg * 64 + tx * 4;
            float4 cv = make_float4(acc[r][cg*4+0], acc[r][cg*4+1],
                                    acc[r][cg*4+2], acc[r][cg*4+3]);
            if constexpr (FUSE_OUT) {
                const float4 rr = *(const float4*)(resid + (size_t)row * N + col);
                cv.x += bb[cg].x + rr.x;
                cv.y += bb[cg].y + rr.y;
                cv.z += bb[cg].z + rr.z;
                cv.w += bb[cg].w + rr.w;
            }
            *(float4*)(Cout + (size_t)row * N + col) = cv;
        }
    }
}

// ---------------------------------------------------------------------------
// fp32 GEMM, 64x64 tile, BK=16, 256 threads, 4x4 micro-tile. For K/V
// projections (M=616, K=2048, N=1280). blockIdx.z picks (Wk->k) vs (Wv->v).
// ---------------------------------------------------------------------------
__global__ __launch_bounds__(256)
void gemm64_kernel(const float* __restrict__ A,
                   const float* __restrict__ B0, const float* __restrict__ B1,
                   float* __restrict__ C0, float* __restrict__ C1,
                   int M, int N, int K)
{
    const float* Bm = blockIdx.z ? B1 : B0;
    float* Cout = blockIdx.z ? C1 : C0;
    __shared__ float As[16][64];
    __shared__ float Bs[16][64];
    const int tid = threadIdx.x;
    const int n0 = blockIdx.x * 64;
    const int m0 = blockIdx.y * 64;
    const int tx = tid & 15, ty = tid >> 4;
    const int ar = tid >> 2;
    const int ak = (tid & 3) << 2;
    const int bk = tid >> 4;
    const int bn = (tid & 15) << 2;

    float acc[4][4] = {};
    const int arow = m0 + ar;
    const bool avalid = arow < M;
    const float* Ap = A + (size_t)arow * K + ak;
    const float* Bp = Bm + (size_t)bk * N + n0 + bn;

    for (int k0 = 0; k0 < K; k0 += 16) {
        const float4 a = avalid ? *(const float4*)(Ap + k0) : make_float4(0.f,0.f,0.f,0.f);
        const float4 b = *(const float4*)(Bp + (size_t)k0 * N);
        __syncthreads();
        As[ak+0][ar] = a.x; As[ak+1][ar] = a.y; As[ak+2][ar] = a.z; As[ak+3][ar] = a.w;
        *(float4*)&Bs[bk][bn] = b;
        __syncthreads();
        #pragma unroll
        for (int kk = 0; kk < 16; ++kk) {
            const float4 av = *(const float4*)&As[kk][ty*4];
            const float4 bv = *(const float4*)&Bs[kk][tx*4];
            const float arr[4] = {av.x, av.y, av.z, av.w};
            const float brr[4] = {bv.x, bv.y, bv.z, bv.w};
            #pragma unroll
            for (int r = 0; r < 4; ++r)
                #pragma unroll
                for (int c = 0; c < 4; ++c)
                    acc[r][c] = fmaf(arr[r], brr[c], acc[r][c]);
        }
    }
    #pragma unroll
    for (int r = 0; r < 4; ++r) {
        const int row = m0 + ty * 4 + r;
        if (row < M) {
            const float4 cv = make_float4(acc[r][0], acc[r][1], acc[r][2], acc[r][3]);
            *(float4*)(Cout + (size_t)row * N + n0 + tx * 4) = cv;
        }
    }
}

// ---------------------------------------------------------------------------
// helpers
// ---------------------------------------------------------------------------
__device__ inline float dot64v(const float4* __restrict__ qr, const float* __restrict__ kr)
{
    const float4* k4 = (const float4*)kr;
    float d0 = 0.f, d1 = 0.f, d2 = 0.f, d3 = 0.f;
    #pragma unroll
    for (int i = 0; i < 16; ++i) {
        const float4 kv = k4[i];
        const float4 qv = qr[i];
        d0 = fmaf(qv.x, kv.x, d0);
        d1 = fmaf(qv.y, kv.y, d1);
        d2 = fmaf(qv.z, kv.z, d2);
        d3 = fmaf(qv.w, kv.w, d3);
    }
    return (d0 + d1) + (d2 + d3);
}

__device__ inline bool first_pair(float va, int ia, float vb, int ib)
{
    return (va > vb) || (va == vb && ia < ib);
}

// descending by (value, then index asc) — matches lax.top_k tie-break
__device__ inline void bitonic_desc(float* vals, int* idxs, int n, int tid, int nt)
{
    for (int k = 2; k <= n; k <<= 1) {
        for (int j = k >> 1; j > 0; j >>= 1) {
            __syncthreads();
            for (int i = tid; i < n; i += nt) {
                const int l = i ^ j;
                if (l > i) {
                    const float vi = vals[i], vl = vals[l];
                    const int   ii = idxs[i], il = idxs[l];
                    const bool up = (i & k) == 0;
                    const bool sw = up ? first_pair(vl, il, vi, ii)
                                       : first_pair(vi, ii, vl, il);
                    if (sw) { vals[i] = vl; vals[l] = vi; idxs[i] = il; idxs[l] = ii; }
                }
            }
        }
    }
    __syncthreads();
}

// ---------------------------------------------------------------------------
// Pass A: first attention, accumulate sum of probs over (h,s) per (b,t).
// Grid: 2560 blocks = b(8) x h(20) x s-chunk(16); 256 threads = 256 s values.
// ---------------------------------------------------------------------------
__global__ __launch_bounds__(256)
void pass_a_kernel(const float* __restrict__ q, const float* __restrict__ kbuf,
                   float* __restrict__ tokp)
{
    __shared__ float sk[T_ * D_];
    __shared__ float wsum[4][T_];
    const int g = blockIdx.x;
    const int b = g / 320;
    const int rem = g % 320;
    const int h = rem >> 4;
    const int chunk = rem & 15;
    const int tid = threadIdx.x;

    for (int i = tid; i < T_ * D_; i += 256) {
        const int t = i >> 6, d = i & 63;
        sk[i] = kbuf[(size_t)b * T_ * HD_ + (size_t)t * HD_ + h * D_ + d];
    }
    __syncthreads();

    const int s = chunk * 256 + tid;
    const float* qp = q + (size_t)(b * S_ + s) * HD_ + h * D_;
    float4 qr[16];
    #pragma unroll
    for (int i = 0; i < 16; ++i) qr[i] = *(const float4*)(qp + 4 * i);

    float mx = -1e30f, L = 0.f;
    for (int t = 0; t < T_; ++t) {
        const float l = dot64v(qr, sk + t * D_) * SCALE_;
        const float nm = fmaxf(mx, l);
        L = L * __expf(mx - nm) + __expf(l - nm);
        mx = nm;
    }
    const float invL = 1.0f / L;
    const int wid = tid >> 6;
    const int lane = tid & 63;
    for (int t = 0; t < T_; ++t) {
        const float l = dot64v(qr, sk + t * D_) * SCALE_;
        float p = __expf(l - mx) * invL;
        #pragma unroll
        for (int off = 32; off > 0; off >>= 1) p += __shfl_xor(p, off, 64);
        if (lane == 0) wsum[wid][t] = p;
    }
    __syncthreads();
    for (int t = tid; t < T_; t += 256)
        tokp[(size_t)g * T_ + t] = (wsum[0][t] + wsum[1][t]) + (wsum[2][t] + wsum[3][t]);
}

// ---------------------------------------------------------------------------
// Top-k over 77 token scores per batch -> tok_mask. 8 blocks x 128 threads.
// ---------------------------------------------------------------------------
__global__ __launch_bounds__(128)
void topk_tok_kernel(const float* __restrict__ tokp, float* __restrict__ tokm)
{
    __shared__ float vals[128];
    __shared__ int idxs[128];
    const int b = blockIdx.x, tid = threadIdx.x;
    float v = -1e30f;
    if (tid < T_) {
        float sm = 0.f;
        for (int j = 0; j < 320; ++j) sm += tokp[(size_t)(b * 320 + j) * T_ + tid];
        v = sm;
    }
    vals[tid] = v; idxs[tid] = tid;
    bitonic_desc(vals, idxs, 128, tid, 128);
    if (tid < T_) tokm[b * T_ + tid] = 0.f;
    __syncthreads();
    if (tid < KTOK_) tokm[b * T_ + idxs[tid]] = 1.0f;
}

// ---------------------------------------------------------------------------
// K/V cross-frame mixing: kd = k2-k (delta), v2 = mixed v. 385 blocks x 256.
// ---------------------------------------------------------------------------
__global__ __launch_bounds__(256)
void mix_kernel(const float* __restrict__ kbuf, const float* __restrict__ vbuf,
                const float* __restrict__ tokm,
                float* __restrict__ kd, float* __restrict__ v2)
{
    const int i = blockIdx.x * 256 + threadIdx.x;   // < 77*1280 = 98560
    const int t = i / HD_;
    float ks = 0.f, vs = 0.f;
    #pragma unroll
    for (int b = 0; b < B_; ++b) {
        ks += kbuf[(size_t)b * T_ * HD_ + i];
        vs += vbuf[(size_t)b * T_ * HD_ + i];
    }
    #pragma unroll
    for (int b = 0; b < B_; ++b) {
        const size_t gi = (size_t)b * T_ * HD_ + i;
        const float msk = tokm[b * T_ + t];
        const float kx = kbuf[gi], vx = vbuf[gi];
        kd[gi] = CMIX_ * msk * ((ks - 8.f * kx) * (1.0f / 7.0f));
        v2[gi] = vx + CMIX_ * msk * ((vs - 8.f * vx) * (1.0f / 7.0f));
    }
}

// ---------------------------------------------------------------------------
// Fused pass B+C: per (b,h,s) row, compute masked prob-mass from ORIGINAL k
// (pos score partial) and second-attention context from k2=k+kd, v2.
// ---------------------------------------------------------------------------
__global__ __launch_bounds__(256)
void pass_bc_kernel(const float* __restrict__ q, const float* __restrict__ kbuf,
                    const float* __restrict__ kd, const float* __restrict__ v2,
                    const float* __restrict__ tokm,
                    float* __restrict__ posp, float* __restrict__ ctx)
{
    __shared__ float sk[T_ * D_];
    __shared__ float sd[T_ * D_];
    __shared__ float sv[T_ * D_];
    __shared__ int smask[T_];
    const int g = blockIdx.x;
    const int b = g / 320;
    const int rem = g % 320;
    const int h = rem >> 4;
    const int chunk = rem & 15;
    const int tid = threadIdx.x;

    for (int i = tid; i < T_ * D_; i += 256) {
        const int t = i >> 6, d = i & 63;
        const size_t gi = (size_t)b * T_ * HD_ + (size_t)t * HD_ + h * D_ + d;
        sk[i] = kbuf[gi];
        sd[i] = kd[gi];
        sv[i] = v2[gi];
    }
    for (int t = tid; t < T_; t += 256) smask[t] = (tokm[b * T_ + t] > 0.5f) ? 1 : 0;
    __syncthreads();

    const int s = chunk * 256 + tid;
    const float* qp = q + (size_t)(b * S_ + s) * HD_ + h * D_;
    float4 qr[16];
    #pragma unroll
    for (int i = 0; i < 16; ++i) qr[i] = *(const float4*)(qp + 4 * i);

    float m1 = -1e30f, L1 = 0.f, Sm = 0.f;
    float m2 = -1e30f, L2 = 0.f;
    for (int t = 0; t < T_; ++t) {
        const float l1 = dot64v(qr, sk + t * D_) * SCALE_;
        float l2 = l1;
        const int msk = smask[t];
        if (msk) l2 = l1 + dot64v(qr, sd + t * D_) * SCALE_;
        const float nm1 = fmaxf(m1, l1);
        const float sc1 = __expf(m1 - nm1);
        const float e1  = __expf(l1 - nm1);
        L1 = L1 * sc1 + e1;
        Sm = Sm * sc1 + (msk ? e1 : 0.f);
        m1 = nm1;
        const float nm2 = fmaxf(m2, l2);
        L2 = L2 * __expf(m2 - nm2) + __expf(l2 - nm2);
        m2 = nm2;
    }
    posp[(size_t)(b * H_ + h) * S_ + s] = Sm / L1;

    const float invL2 = 1.0f / L2;
    float4 cacc[16] = {};
    for (int t = 0; t < T_; ++t) {
        float l2 = dot64v(qr, sk + t * D_) * SCALE_;
        if (smask[t]) l2 += dot64v(qr, sd + t * D_) * SCALE_;
        const float p = __expf(l2 - m2) * invL2;
        const float4* vv = (const float4*)(sv + t * D_);
        #pragma unroll
        for (int i = 0; i < 16; ++i) {
            const float4 vx = vv[i];
            cacc[i].x = fmaf(p, vx.x, cacc[i].x);
            cacc[i].y = fmaf(p, vx.y, cacc[i].y);
            cacc[i].z = fmaf(p, vx.z, cacc[i].z);
            cacc[i].w = fmaf(p, vx.w, cacc[i].w);
        }
    }
    float* cp = ctx + (size_t)(b * S_ + s) * HD_ + h * D_;
    #pragma unroll
    for (int i = 0; i < 16; ++i) *(float4*)(cp + 4 * i) = cacc[i];
}

// ---------------------------------------------------------------------------
// Top-k over 4096 position scores per batch -> pos_mask. 8 blocks x 1024.
// ---------------------------------------------------------------------------
__global__ __launch_bounds__(1024)
void topk_pos_kernel(const float* __restrict__ posp, float* __restrict__ posm)
{
    __shared__ float vals[S_];
    __shared__ int idxs[S_];
    const int b = blockIdx.x, tid = threadIdx.x;
    for (int s = tid; s < S_; s += 1024) {
        float sm = 0.f;
        for (int h = 0; h < H_; ++h) sm += posp[(size_t)(b * H_ + h) * S_ + s];
        vals[s] = sm; idxs[s] = s;
    }
    bitonic_desc(vals, idxs, S_, tid, 1024);
    for (int s = tid; s < S_; s += 1024) posm[b * S_ + s] = 0.f;
    __syncthreads();
    for (int i = tid; i < KPOS_; i += 1024) posm[b * S_ + idxs[i]] = 1.0f;
}

// ---------------------------------------------------------------------------
// Batch-sum of context over b: csum[s,hd] = sum_b ctx[b,s,hd]. float4 lanes.
// ---------------------------------------------------------------------------
__global__ __launch_bounds__(256)
void ctxsum_kernel(const float* __restrict__ ctx, float* __restrict__ csum)
{
    const size_t i = (size_t)blockIdx.x * 256 + threadIdx.x;  // float4 index
    const float4* c = (const float4*)ctx;
    float4 a = c[i];
    #pragma unroll
    for (int b = 1; b < B_; ++b) {
        const float4 x = c[(size_t)b * (S_ * HD_ / 4) + i];
        a.x += x.x; a.y += x.y; a.z += x.z; a.w += x.w;
    }
    ((float4*)csum)[i] = a;
}

// ---------------------------------------------------------------------------
extern "C" void kernel_launch(void* const* d_in, const int* in_sizes, int n_in,
                              void* d_out, int out_size, void* d_ws, size_t ws_size,
                              hipStream_t stream)
{
    const float* hidden = (const float*)d_in[0];
    const float* enc    = (const float*)d_in[1];
    const float* Wq     = (const float*)d_in[2];
    const float* Wk     = (const float*)d_in[3];
    const float* Wv     = (const float*)d_in[4];
    const float* Wo     = (const float*)d_in[5];
    const float* bo     = (const float*)d_in[6];
    float* out = (float*)d_out;

    float* w = (float*)d_ws;
    size_t o = 0;
    float* q    = w + o; o += (size_t)M1_ * HD_;      // 41,943,040
    float* ctx  = w + o; o += (size_t)M1_ * HD_;      // 41,943,040
    float* kbuf = w + o; o += (size_t)B_ * T_ * HD_;  // 788,480
    float* vbuf = w + o; o += (size_t)B_ * T_ * HD_;
    float* kd   = w + o; o += (size_t)B_ * T_ * HD_;
    float* v2   = w + o; o += (size_t)B_ * T_ * HD_;
    float* csum = w + o; o += (size_t)S_ * HD_;       // 5,242,880
    float* tokp = w + o; o += (size_t)2560 * T_;      // 197,120
    float* posp = w + o; o += (size_t)B_ * H_ * S_;   // 655,360
    float* tokm = w + o; o += B_ * T_;
    float* posm = w + o; o += B_ * S_;
    (void)ws_size; (void)in_sizes; (void)n_in; (void)out_size;

    // 1. Q projection (fp32 exact: feeds the ranking-sensitive scoring path)
    gemm128_kernel<false, false><<<dim3(10, 256), 256, 0, stream>>>(
        hidden, Wq, q, C_, nullptr, nullptr, nullptr, nullptr);
    // 2. K and V projections
    gemm64_kernel<<<dim3(20, 10, 2), 256, 0, stream>>>(
        enc, Wk, Wv, kbuf, vbuf, MKV_, HD_, CENC_);
    // 3. First attention -> token-score partials
    pass_a_kernel<<<2560, 256, 0, stream>>>(q, kbuf, tokp);
    // 4. Token top-k mask
    topk_tok_kernel<<<8, 128, 0, stream>>>(tokp, tokm);
    // 5. Cross-frame K/V mixing
    mix_kernel<<<385, 256, 0, stream>>>(kbuf, vbuf, tokm, kd, v2);
    // 6. Fused pass B (pos scores) + pass C (second attention context)
    pass_bc_kernel<<<2560, 256, 0, stream>>>(q, kbuf, kd, v2, tokm, posp, ctx);
    // 7. Position top-k mask
    topk_pos_kernel<<<8, 1024, 0, stream>>>(posp, posm);
    // 8. Batch-sum of context for mean-of-others injection
    ctxsum_kernel<<<S_ * HD_ / 4 / 256, 256, 0, stream>>>(ctx, csum);
    // 9. Injection + output projection + bias + residual
    gemm128_kernel<true, true><<<dim3(10, 256), 256, 0, stream>>>(
        ctx, Wo, out, HD_, posm, csum, bo, hidden);
}

// Round 2
// 2436.663 us; speedup vs baseline: 1.5454x; 1.5454x over previous
//
#include <hip/hip_runtime.h>
#include <math.h>

// Problem constants
#define B_    8
#define S_    4096
#define T_    77
#define C_    1280
#define CENC_ 2048
#define H_    20
#define D_    64
#define HD_   1280
#define M1_   (B_*S_)     // 32768 rows for Q / O GEMMs
#define MKV_  (B_*T_)     // 616 rows for K/V GEMM
#define KTOK_ 12          // ceil(77*0.15)
#define KPOS_ 1229        // ceil(4096*0.3)
#define SCALE_ 0.125f     // 1/sqrt(64)
#define CMIX_  0.15f      // STRENGTH*(1-ALPHA)
#define CINJ_  (0.25f/7.0f) // FIW*STRENGTH/(B-1)

typedef __attribute__((ext_vector_type(8))) short bf16x8;
typedef __attribute__((ext_vector_type(4))) float f32x4;

#define AS_G __attribute__((address_space(1)))
#define AS_L __attribute__((address_space(3)))

// ---------------------------------------------------------------------------
// bf16 helpers (RNE)
// ---------------------------------------------------------------------------
__device__ inline unsigned short f2bf(float x)
{
    union { float f; unsigned u; } v; v.f = x;
    const unsigned r = v.u + 0x7FFFu + ((v.u >> 16) & 1u);
    return (unsigned short)(r >> 16);
}
__device__ inline float bf2f(unsigned short h)
{
    union { float f; unsigned u; } v; v.u = ((unsigned)h) << 16;
    return v.f;
}

// ---------------------------------------------------------------------------
// Split fp32 -> bf16 hi + bf16 lo (residual). One float4 per thread.
// ---------------------------------------------------------------------------
__global__ __launch_bounds__(256)
void split_convert_kernel(const float* __restrict__ x, unsigned short* __restrict__ hi,
                          unsigned short* __restrict__ lo)
{
    const size_t i4 = (size_t)blockIdx.x * 256 + threadIdx.x;
    const float4 v = ((const float4*)x)[i4];
    ushort4 h, l;
    h.x = f2bf(v.x); l.x = f2bf(v.x - bf2f(h.x));
    h.y = f2bf(v.y); l.y = f2bf(v.y - bf2f(h.y));
    h.z = f2bf(v.z); l.z = f2bf(v.z - bf2f(h.z));
    h.w = f2bf(v.w); l.w = f2bf(v.w - bf2f(h.w));
    ((ushort4*)hi)[i4] = h;
    ((ushort4*)lo)[i4] = l;
}

// ---------------------------------------------------------------------------
// Weight transpose + split: W[K=1280][N=1280] fp32 -> Thi/Tlo [N][K] bf16.
// 32x32 LDS tiles, grid (40,40), 256 threads (32x8).
// ---------------------------------------------------------------------------
__global__ __launch_bounds__(256)
void wsplitT_kernel(const float* __restrict__ W, unsigned short* __restrict__ Thi,
                    unsigned short* __restrict__ Tlo)
{
    __shared__ float tile[32][33];
    const int tx = threadIdx.x & 31, ty = threadIdx.x >> 5;
    const int n0 = blockIdx.x * 32, k0 = blockIdx.y * 32;
    #pragma unroll
    for (int i = 0; i < 4; ++i) {
        const int kk = ty + i * 8;
        tile[kk][tx] = W[(size_t)(k0 + kk) * 1280 + n0 + tx];
    }
    __syncthreads();
    #pragma unroll
    for (int i = 0; i < 4; ++i) {
        const int nn = ty + i * 8;
        const float v = tile[tx][nn];               // = W[k0+tx][n0+nn]
        const unsigned short h = f2bf(v);
        const size_t oi = (size_t)(n0 + nn) * 1280 + k0 + tx;
        Thi[oi] = h;
        Tlo[oi] = f2bf(v - bf2f(h));
    }
}

// ---------------------------------------------------------------------------
// Injection + fp32->bf16 for the O-projection A operand:
// a = ctx*(1-8*cf) + cf*csum, cf = posm[row]*CINJ_.
// ---------------------------------------------------------------------------
__global__ __launch_bounds__(256)
void inject_convert_kernel(const float* __restrict__ ctx, const float* __restrict__ csum,
                           const float* __restrict__ posm, unsigned short* __restrict__ outb)
{
    const size_t i4 = (size_t)blockIdx.x * 256 + threadIdx.x;   // float4 index
    const int row = (int)(i4 / 320);
    const int c4  = (int)(i4 % 320);
    const float cf = posm[row] * CINJ_;
    const float am = 1.0f - 8.0f * cf;
    const float4 c  = ((const float4*)ctx)[i4];
    const float4 cs = ((const float4*)csum)[(size_t)(row & (S_ - 1)) * 320 + c4];
    ushort4 h;
    h.x = f2bf(c.x * am + cf * cs.x);
    h.y = f2bf(c.y * am + cf * cs.y);
    h.z = f2bf(c.z * am + cf * cs.z);
    h.w = f2bf(c.w * am + cf * cs.w);
    ((ushort4*)outb)[i4] = h;
}

// ---------------------------------------------------------------------------
// MFMA GEMM: C[M x 1280] = A[M x K] * B[K x 1280], A and B^T given in bf16.
// 128x128 tile, BK=32, 4 waves (2x2 of 64x64), 16x16x32 bf16 MFMA.
// SPLIT: A/B given as hi+lo pairs; acc += Ah*Bh + Ah*Bl + Al*Bh (fp32-ish).
// FUSE_OUT: epilogue adds bias[col] + resid[row][col].
// Staging via global_load_lds width=16 (wave-uniform base + lane*16).
// ---------------------------------------------------------------------------
__device__ inline void stage_tile(const unsigned short* __restrict__ gsrc,
                                  unsigned short* lds, int tid, int ldK,
                                  int row0, int k0)
{
    #pragma unroll
    for (int c0 = 0; c0 < 512; c0 += 256) {
        const int c = c0 + tid;
        const unsigned short* gp = gsrc + (size_t)(row0 + (c >> 2)) * ldK + k0 + (c & 3) * 8;
        __builtin_amdgcn_global_load_lds((const AS_G void*)gp, (AS_L void*)(lds + (size_t)c * 8),
                                         16, 0, 0);
    }
}

template<bool SPLIT, bool FUSE_OUT>
__global__ __launch_bounds__(256)
void mfma_gemm_kernel(const unsigned short* __restrict__ Ahi, const unsigned short* __restrict__ Alo,
                      const unsigned short* __restrict__ BhiT, const unsigned short* __restrict__ BloT,
                      float* __restrict__ Cout, int K,
                      const float* __restrict__ bias, const float* __restrict__ resid)
{
    __shared__ unsigned short sAhi[128 * 32];
    __shared__ unsigned short sBhi[128 * 32];
    __shared__ unsigned short sAlo[SPLIT ? 128 * 32 : 8];
    __shared__ unsigned short sBlo[SPLIT ? 128 * 32 : 8];

    const int tid  = threadIdx.x;
    const int lane = tid & 63;
    const int wave = tid >> 6;
    const int quad = lane >> 4;
    const int lrow = lane & 15;
    const int wm = (wave & 1) * 64;
    const int wn = (wave >> 1) * 64;
    const int n0 = blockIdx.x * 128;
    const int m0 = blockIdx.y * 128;

    f32x4 acc[4][4] = {};

    for (int k0 = 0; k0 < K; k0 += 32) {
        __syncthreads();
        stage_tile(Ahi,  sAhi, tid, K, m0, k0);
        stage_tile(BhiT, sBhi, tid, K, n0, k0);
        if constexpr (SPLIT) {
            stage_tile(Alo,  sAlo, tid, K, m0, k0);
            stage_tile(BloT, sBlo, tid, K, n0, k0);
        }
        __syncthreads();

        bf16x8 ah[4], bh[4];
        #pragma unroll
        for (int i = 0; i < 4; ++i) {
            ah[i] = *(const bf16x8*)(sAhi + (wm + i * 16 + lrow) * 32 + quad * 8);
            bh[i] = *(const bf16x8*)(sBhi + (wn + i * 16 + lrow) * 32 + quad * 8);
        }
        if constexpr (SPLIT) {
            bf16x8 al[4], bl[4];
            #pragma unroll
            for (int i = 0; i < 4; ++i) {
                al[i] = *(const bf16x8*)(sAlo + (wm + i * 16 + lrow) * 32 + quad * 8);
                bl[i] = *(const bf16x8*)(sBlo + (wn + i * 16 + lrow) * 32 + quad * 8);
            }
            #pragma unroll
            for (int mt = 0; mt < 4; ++mt)
                #pragma unroll
                for (int nt = 0; nt < 4; ++nt) {
                    acc[mt][nt] = __builtin_amdgcn_mfma_f32_16x16x32_bf16(ah[mt], bh[nt], acc[mt][nt], 0, 0, 0);
                    acc[mt][nt] = __builtin_amdgcn_mfma_f32_16x16x32_bf16(ah[mt], bl[nt], acc[mt][nt], 0, 0, 0);
                    acc[mt][nt] = __builtin_amdgcn_mfma_f32_16x16x32_bf16(al[mt], bh[nt], acc[mt][nt], 0, 0, 0);
                }
        } else {
            #pragma unroll
            for (int mt = 0; mt < 4; ++mt)
                #pragma unroll
                for (int nt = 0; nt < 4; ++nt)
                    acc[mt][nt] = __builtin_amdgcn_mfma_f32_16x16x32_bf16(ah[mt], bh[nt], acc[mt][nt], 0, 0, 0);
        }
    }

    // Epilogue: C/D layout col = lane&15, row = quad*4 + reg (m89/m91-verified)
    #pragma unroll
    for (int mt = 0; mt < 4; ++mt) {
        #pragma unroll
        for (int nt = 0; nt < 4; ++nt) {
            const int col = n0 + wn + nt * 16 + lrow;
            #pragma unroll
            for (int r = 0; r < 4; ++r) {
                const int row = m0 + wm + mt * 16 + quad * 4 + r;
                float v = acc[mt][nt][r];
                if constexpr (FUSE_OUT)
                    v += bias[col] + resid[(size_t)row * 1280 + col];
                Cout[(size_t)row * 1280 + col] = v;
            }
        }
    }
}

// ---------------------------------------------------------------------------
// fp32 GEMM, 64x64 tile, BK=16, 256 threads, 4x4 micro-tile. For K/V
// projections (M=616, K=2048, N=1280) — stays fp32 (feeds scoring path).
// ---------------------------------------------------------------------------
__global__ __launch_bounds__(256)
void gemm64_kernel(const float* __restrict__ A,
                   const float* __restrict__ B0, const float* __restrict__ B1,
                   float* __restrict__ C0, float* __restrict__ C1,
                   int M, int N, int K)
{
    const float* Bm = blockIdx.z ? B1 : B0;
    float* Cout = blockIdx.z ? C1 : C0;
    __shared__ float As[16][64];
    __shared__ float Bs[16][64];
    const int tid = threadIdx.x;
    const int n0 = blockIdx.x * 64;
    const int m0 = blockIdx.y * 64;
    const int tx = tid & 15, ty = tid >> 4;
    const int ar = tid >> 2;
    const int ak = (tid & 3) << 2;
    const int bk = tid >> 4;
    const int bn = (tid & 15) << 2;

    float acc[4][4] = {};
    const int arow = m0 + ar;
    const bool avalid = arow < M;
    const float* Ap = A + (size_t)arow * K + ak;
    const float* Bp = Bm + (size_t)bk * N + n0 + bn;

    for (int k0 = 0; k0 < K; k0 += 16) {
        const float4 a = avalid ? *(const float4*)(Ap + k0) : make_float4(0.f,0.f,0.f,0.f);
        const float4 b = *(const float4*)(Bp + (size_t)k0 * N);
        __syncthreads();
        As[ak+0][ar] = a.x; As[ak+1][ar] = a.y; As[ak+2][ar] = a.z; As[ak+3][ar] = a.w;
        *(float4*)&Bs[bk][bn] = b;
        __syncthreads();
        #pragma unroll
        for (int kk = 0; kk < 16; ++kk) {
            const float4 av = *(const float4*)&As[kk][ty*4];
            const float4 bv = *(const float4*)&Bs[kk][tx*4];
            const float arr[4] = {av.x, av.y, av.z, av.w};
            const float brr[4] = {bv.x, bv.y, bv.z, bv.w};
            #pragma unroll
            for (int r = 0; r < 4; ++r)
                #pragma unroll
                for (int c = 0; c < 4; ++c)
                    acc[r][c] = fmaf(arr[r], brr[c], acc[r][c]);
        }
    }
    #pragma unroll
    for (int r = 0; r < 4; ++r) {
        const int row = m0 + ty * 4 + r;
        if (row < M) {
            const float4 cv = make_float4(acc[r][0], acc[r][1], acc[r][2], acc[r][3]);
            *(float4*)(Cout + (size_t)row * N + n0 + tx * 4) = cv;
        }
    }
}

// ---------------------------------------------------------------------------
// helpers
// ---------------------------------------------------------------------------
__device__ inline float dot64v(const float4* __restrict__ qr, const float* __restrict__ kr)
{
    const float4* k4 = (const float4*)kr;
    float d0 = 0.f, d1 = 0.f, d2 = 0.f, d3 = 0.f;
    #pragma unroll
    for (int i = 0; i < 16; ++i) {
        const float4 kv = k4[i];
        const float4 qv = qr[i];
        d0 = fmaf(qv.x, kv.x, d0);
        d1 = fmaf(qv.y, kv.y, d1);
        d2 = fmaf(qv.z, kv.z, d2);
        d3 = fmaf(qv.w, kv.w, d3);
    }
    return (d0 + d1) + (d2 + d3);
}

__device__ inline bool first_pair(float va, int ia, float vb, int ib)
{
    return (va > vb) || (va == vb && ia < ib);
}

// descending by (value, then index asc) — matches lax.top_k tie-break
__device__ inline void bitonic_desc(float* vals, int* idxs, int n, int tid, int nt)
{
    for (int k = 2; k <= n; k <<= 1) {
        for (int j = k >> 1; j > 0; j >>= 1) {
            __syncthreads();
            for (int i = tid; i < n; i += nt) {
                const int l = i ^ j;
                if (l > i) {
                    const float vi = vals[i], vl = vals[l];
                    const int   ii = idxs[i], il = idxs[l];
                    const bool up = (i & k) == 0;
                    const bool sw = up ? first_pair(vl, il, vi, ii)
                                       : first_pair(vi, ii, vl, il);
                    if (sw) { vals[i] = vl; vals[l] = vi; idxs[i] = il; idxs[l] = ii; }
                }
            }
        }
    }
    __syncthreads();
}

// ---------------------------------------------------------------------------
// Pass A: first attention, accumulate sum of probs over (h,s) per (b,t).
// Grid: 2560 blocks = b(8) x h(20) x s-chunk(16); 256 threads = 256 s values.
// ---------------------------------------------------------------------------
__global__ __launch_bounds__(256)
void pass_a_kernel(const float* __restrict__ q, const float* __restrict__ kbuf,
                   float* __restrict__ tokp)
{
    __shared__ float sk[T_ * D_];
    __shared__ float wsum[4][T_];
    const int g = blockIdx.x;
    const int b = g / 320;
    const int rem = g % 320;
    const int h = rem >> 4;
    const int chunk = rem & 15;
    const int tid = threadIdx.x;

    for (int i = tid; i < T_ * D_; i += 256) {
        const int t = i >> 6, d = i & 63;
        sk[i] = kbuf[(size_t)b * T_ * HD_ + (size_t)t * HD_ + h * D_ + d];
    }
    __syncthreads();

    const int s = chunk * 256 + tid;
    const float* qp = q + (size_t)(b * S_ + s) * HD_ + h * D_;
    float4 qr[16];
    #pragma unroll
    for (int i = 0; i < 16; ++i) qr[i] = *(const float4*)(qp + 4 * i);

    float mx = -1e30f, L = 0.f;
    for (int t = 0; t < T_; ++t) {
        const float l = dot64v(qr, sk + t * D_) * SCALE_;
        const float nm = fmaxf(mx, l);
        L = L * __expf(mx - nm) + __expf(l - nm);
        mx = nm;
    }
    const float invL = 1.0f / L;
    const int wid = tid >> 6;
    const int lane = tid & 63;
    for (int t = 0; t < T_; ++t) {
        const float l = dot64v(qr, sk + t * D_) * SCALE_;
        float p = __expf(l - mx) * invL;
        #pragma unroll
        for (int off = 32; off > 0; off >>= 1) p += __shfl_xor(p, off, 64);
        if (lane == 0) wsum[wid][t] = p;
    }
    __syncthreads();
    for (int t = tid; t < T_; t += 256)
        tokp[(size_t)g * T_ + t] = (wsum[0][t] + wsum[1][t]) + (wsum[2][t] + wsum[3][t]);
}

// ---------------------------------------------------------------------------
// Top-k over 77 token scores per batch -> tok_mask. 8 blocks x 128 threads.
// ---------------------------------------------------------------------------
__global__ __launch_bounds__(128)
void topk_tok_kernel(const float* __restrict__ tokp, float* __restrict__ tokm)
{
    __shared__ float vals[128];
    __shared__ int idxs[128];
    const int b = blockIdx.x, tid = threadIdx.x;
    float v = -1e30f;
    if (tid < T_) {
        float sm = 0.f;
        for (int j = 0; j < 320; ++j) sm += tokp[(size_t)(b * 320 + j) * T_ + tid];
        v = sm;
    }
    vals[tid] = v; idxs[tid] = tid;
    bitonic_desc(vals, idxs, 128, tid, 128);
    if (tid < T_) tokm[b * T_ + tid] = 0.f;
    __syncthreads();
    if (tid < KTOK_) tokm[b * T_ + idxs[tid]] = 1.0f;
}

// ---------------------------------------------------------------------------
// K/V cross-frame mixing: kd = k2-k (delta), v2 = mixed v. 385 blocks x 256.
// ---------------------------------------------------------------------------
__global__ __launch_bounds__(256)
void mix_kernel(const float* __restrict__ kbuf, const float* __restrict__ vbuf,
                const float* __restrict__ tokm,
                float* __restrict__ kd, float* __restrict__ v2)
{
    const int i = blockIdx.x * 256 + threadIdx.x;   // < 77*1280 = 98560
    const int t = i / HD_;
    float ks = 0.f, vs = 0.f;
    #pragma unroll
    for (int b = 0; b < B_; ++b) {
        ks += kbuf[(size_t)b * T_ * HD_ + i];
        vs += vbuf[(size_t)b * T_ * HD_ + i];
    }
    #pragma unroll
    for (int b = 0; b < B_; ++b) {
        const size_t gi = (size_t)b * T_ * HD_ + i;
        const float msk = tokm[b * T_ + t];
        const float kx = kbuf[gi], vx = vbuf[gi];
        kd[gi] = CMIX_ * msk * ((ks - 8.f * kx) * (1.0f / 7.0f));
        v2[gi] = vx + CMIX_ * msk * ((vs - 8.f * vx) * (1.0f / 7.0f));
    }
}

// ---------------------------------------------------------------------------
// Fused pass B+C: per (b,h,s) row, compute masked prob-mass from ORIGINAL k
// (pos score partial) and second-attention context from k2=k+kd, v2.
// ---------------------------------------------------------------------------
__global__ __launch_bounds__(256)
void pass_bc_kernel(const float* __restrict__ q, const float* __restrict__ kbuf,
                    const float* __restrict__ kd, const float* __restrict__ v2,
                    const float* __restrict__ tokm,
                    float* __restrict__ posp, float* __restrict__ ctx)
{
    __shared__ float sk[T_ * D_];
    __shared__ float sd[T_ * D_];
    __shared__ float sv[T_ * D_];
    __shared__ int smask[T_];
    const int g = blockIdx.x;
    const int b = g / 320;
    const int rem = g % 320;
    const int h = rem >> 4;
    const int chunk = rem & 15;
    const int tid = threadIdx.x;

    for (int i = tid; i < T_ * D_; i += 256) {
        const int t = i >> 6, d = i & 63;
        const size_t gi = (size_t)b * T_ * HD_ + (size_t)t * HD_ + h * D_ + d;
        sk[i] = kbuf[gi];
        sd[i] = kd[gi];
        sv[i] = v2[gi];
    }
    for (int t = tid; t < T_; t += 256) smask[t] = (tokm[b * T_ + t] > 0.5f) ? 1 : 0;
    __syncthreads();

    const int s = chunk * 256 + tid;
    const float* qp = q + (size_t)(b * S_ + s) * HD_ + h * D_;
    float4 qr[16];
    #pragma unroll
    for (int i = 0; i < 16; ++i) qr[i] = *(const float4*)(qp + 4 * i);

    float m1 = -1e30f, L1 = 0.f, Sm = 0.f;
    float m2 = -1e30f, L2 = 0.f;
    for (int t = 0; t < T_; ++t) {
        const float l1 = dot64v(qr, sk + t * D_) * SCALE_;
        float l2 = l1;
        const int msk = smask[t];
        if (msk) l2 = l1 + dot64v(qr, sd + t * D_) * SCALE_;
        const float nm1 = fmaxf(m1, l1);
        const float sc1 = __expf(m1 - nm1);
        const float e1  = __expf(l1 - nm1);
        L1 = L1 * sc1 + e1;
        Sm = Sm * sc1 + (msk ? e1 : 0.f);
        m1 = nm1;
        const float nm2 = fmaxf(m2, l2);
        L2 = L2 * __expf(m2 - nm2) + __expf(l2 - nm2);
        m2 = nm2;
    }
    posp[(size_t)(b * H_ + h) * S_ + s] = Sm / L1;

    const float invL2 = 1.0f / L2;
    float4 cacc[16] = {};
    for (int t = 0; t < T_; ++t) {
        float l2 = dot64v(qr, sk + t * D_) * SCALE_;
        if (smask[t]) l2 += dot64v(qr, sd + t * D_) * SCALE_;
        const float p = __expf(l2 - m2) * invL2;
        const float4* vv = (const float4*)(sv + t * D_);
        #pragma unroll
        for (int i = 0; i < 16; ++i) {
            const float4 vx = vv[i];
            cacc[i].x = fmaf(p, vx.x, cacc[i].x);
            cacc[i].y = fmaf(p, vx.y, cacc[i].y);
            cacc[i].z = fmaf(p, vx.z, cacc[i].z);
            cacc[i].w = fmaf(p, vx.w, cacc[i].w);
        }
    }
    float* cp = ctx + (size_t)(b * S_ + s) * HD_ + h * D_;
    #pragma unroll
    for (int i = 0; i < 16; ++i) *(float4*)(cp + 4 * i) = cacc[i];
}

// ---------------------------------------------------------------------------
// Top-k over 4096 position scores per batch -> pos_mask. 8 blocks x 1024.
// ---------------------------------------------------------------------------
__global__ __launch_bounds__(1024)
void topk_pos_kernel(const float* __restrict__ posp, float* __restrict__ posm)
{
    __shared__ float vals[S_];
    __shared__ int idxs[S_];
    const int b = blockIdx.x, tid = threadIdx.x;
    for (int s = tid; s < S_; s += 1024) {
        float sm = 0.f;
        for (int h = 0; h < H_; ++h) sm += posp[(size_t)(b * H_ + h) * S_ + s];
        vals[s] = sm; idxs[s] = s;
    }
    bitonic_desc(vals, idxs, S_, tid, 1024);
    for (int s = tid; s < S_; s += 1024) posm[b * S_ + s] = 0.f;
    __syncthreads();
    for (int i = tid; i < KPOS_; i += 1024) posm[b * S_ + idxs[i]] = 1.0f;
}

// ---------------------------------------------------------------------------
// Batch-sum of context over b: csum[s,hd] = sum_b ctx[b,s,hd]. float4 lanes.
// ---------------------------------------------------------------------------
__global__ __launch_bounds__(256)
void ctxsum_kernel(const float* __restrict__ ctx, float* __restrict__ csum)
{
    const size_t i = (size_t)blockIdx.x * 256 + threadIdx.x;  // float4 index
    const float4* c = (const float4*)ctx;
    float4 a = c[i];
    #pragma unroll
    for (int b = 1; b < B_; ++b) {
        const float4 x = c[(size_t)b * (S_ * HD_ / 4) + i];
        a.x += x.x; a.y += x.y; a.z += x.z; a.w += x.w;
    }
    ((float4*)csum)[i] = a;
}

// ---------------------------------------------------------------------------
extern "C" void kernel_launch(void* const* d_in, const int* in_sizes, int n_in,
                              void* d_out, int out_size, void* d_ws, size_t ws_size,
                              hipStream_t stream)
{
    const float* hidden = (const float*)d_in[0];
    const float* enc    = (const float*)d_in[1];
    const float* Wq     = (const float*)d_in[2];
    const float* Wk     = (const float*)d_in[3];
    const float* Wv     = (const float*)d_in[4];
    const float* Wo     = (const float*)d_in[5];
    const float* bo     = (const float*)d_in[6];
    float* out = (float*)d_out;

    char* w = (char*)d_ws;
    float* q    = (float*)w; w += (size_t)M1_ * HD_ * 4;
    float* ctx  = (float*)w; w += (size_t)M1_ * HD_ * 4;
    float* kbuf = (float*)w; w += (size_t)B_ * T_ * HD_ * 4;
    float* vbuf = (float*)w; w += (size_t)B_ * T_ * HD_ * 4;
    float* kd   = (float*)w; w += (size_t)B_ * T_ * HD_ * 4;
    float* v2   = (float*)w; w += (size_t)B_ * T_ * HD_ * 4;
    float* csum = (float*)w; w += (size_t)S_ * HD_ * 4;
    float* tokp = (float*)w; w += (size_t)2560 * T_ * 4;
    float* posp = (float*)w; w += (size_t)B_ * H_ * S_ * 4;
    float* tokm = (float*)w; w += (size_t)B_ * T_ * 4;
    float* posm = (float*)w; w += (size_t)B_ * S_ * 4;
    unsigned short* Ahi   = (unsigned short*)w; w += (size_t)M1_ * HD_ * 2;
    unsigned short* Alo   = (unsigned short*)w; w += (size_t)M1_ * HD_ * 2;
    unsigned short* ctxb  = (unsigned short*)w; w += (size_t)M1_ * HD_ * 2;
    unsigned short* WqhiT = (unsigned short*)w; w += (size_t)C_ * HD_ * 2;
    unsigned short* WqloT = (unsigned short*)w; w += (size_t)C_ * HD_ * 2;
    unsigned short* WohiT = (unsigned short*)w; w += (size_t)HD_ * C_ * 2;
    unsigned short* WoloT = (unsigned short*)w; w += (size_t)HD_ * C_ * 2;
    (void)ws_size; (void)in_sizes; (void)n_in; (void)out_size;

    // 1. Split hidden -> bf16 hi/lo; weights -> transposed bf16 hi/lo
    split_convert_kernel<<<M1_ * HD_ / 4 / 256, 256, 0, stream>>>(hidden, Ahi, Alo);
    wsplitT_kernel<<<dim3(40, 40), 256, 0, stream>>>(Wq, WqhiT, WqloT);
    wsplitT_kernel<<<dim3(40, 40), 256, 0, stream>>>(Wo, WohiT, WoloT);
    // 2. Q projection: split-bf16 MFMA (3 products ~ fp32 accuracy)
    mfma_gemm_kernel<true, false><<<dim3(10, 256), 256, 0, stream>>>(
        Ahi, Alo, WqhiT, WqloT, q, C_, nullptr, nullptr);
    // 3. K and V projections (fp32 — feeds scoring logits)
    gemm64_kernel<<<dim3(20, 10, 2), 256, 0, stream>>>(
        enc, Wk, Wv, kbuf, vbuf, MKV_, HD_, CENC_);
    // 4. First attention -> token-score partials
    pass_a_kernel<<<2560, 256, 0, stream>>>(q, kbuf, tokp);
    // 5. Token top-k mask
    topk_tok_kernel<<<8, 128, 0, stream>>>(tokp, tokm);
    // 6. Cross-frame K/V mixing
    mix_kernel<<<385, 256, 0, stream>>>(kbuf, vbuf, tokm, kd, v2);
    // 7. Fused pass B (pos scores) + pass C (second attention context)
    pass_bc_kernel<<<2560, 256, 0, stream>>>(q, kbuf, kd, v2, tokm, posp, ctx);
    // 8. Position top-k mask
    topk_pos_kernel<<<8, 1024, 0, stream>>>(posp, posm);
    // 9. Batch-sum of context for mean-of-others injection
    ctxsum_kernel<<<S_ * HD_ / 4 / 256, 256, 0, stream>>>(ctx, csum);
    // 10. Injection + bf16 convert of context (A operand of O-proj)
    inject_convert_kernel<<<M1_ * HD_ / 4 / 256, 256, 0, stream>>>(ctx, csum, posm, ctxb);
    // 11. O projection: plain bf16 MFMA + bias + residual epilogue
    mfma_gemm_kernel<false, true><<<dim3(10, 256), 256, 0, stream>>>(
        ctxb, nullptr, WohiT, nullptr, out, HD_, bo, hidden);
}

// Round 3
// 2199.565 us; speedup vs baseline: 1.7119x; 1.1078x over previous
//
#include <hip/hip_runtime.h>
#include <math.h>

// Problem constants
#define B_    8
#define S_    4096
#define T_    77
#define C_    1280
#define CENC_ 2048
#define H_    20
#define D_    64
#define HD_   1280
#define M1_   (B_*S_)     // 32768 rows for Q / O GEMMs
#define MKV_  (B_*T_)     // 616 rows for K/V GEMM
#define KTOK_ 12          // ceil(77*0.15)
#define KPOS_ 1229        // ceil(4096*0.3)
#define SCALE_ 0.125f     // 1/sqrt(64)
#define CMIX_  0.15f      // STRENGTH*(1-ALPHA)
#define CINJ_  (0.25f/7.0f) // FIW*STRENGTH/(B-1)

typedef __attribute__((ext_vector_type(8))) short bf16x8;
typedef __attribute__((ext_vector_type(4))) float f32x4;

#define AS_G __attribute__((address_space(1)))
#define AS_L __attribute__((address_space(3)))

// ---------------------------------------------------------------------------
// bf16 helpers (RNE)
// ---------------------------------------------------------------------------
__device__ inline unsigned short f2bf(float x)
{
    union { float f; unsigned u; } v; v.f = x;
    const unsigned r = v.u + 0x7FFFu + ((v.u >> 16) & 1u);
    return (unsigned short)(r >> 16);
}
__device__ inline float bf2f(unsigned short h)
{
    union { float f; unsigned u; } v; v.u = ((unsigned)h) << 16;
    return v.f;
}

// ---------------------------------------------------------------------------
// Split fp32 -> bf16 hi + bf16 lo (residual). One float4 per thread.
// ---------------------------------------------------------------------------
__global__ __launch_bounds__(256)
void split_convert_kernel(const float* __restrict__ x, unsigned short* __restrict__ hi,
                          unsigned short* __restrict__ lo)
{
    const size_t i4 = (size_t)blockIdx.x * 256 + threadIdx.x;
    const float4 v = ((const float4*)x)[i4];
    ushort4 h, l;
    h.x = f2bf(v.x); l.x = f2bf(v.x - bf2f(h.x));
    h.y = f2bf(v.y); l.y = f2bf(v.y - bf2f(h.y));
    h.z = f2bf(v.z); l.z = f2bf(v.z - bf2f(h.z));
    h.w = f2bf(v.w); l.w = f2bf(v.w - bf2f(h.w));
    ((ushort4*)hi)[i4] = h;
    ((ushort4*)lo)[i4] = l;
}

// ---------------------------------------------------------------------------
// Weight transpose + split: W[K=1280][N=1280] fp32 -> Thi/Tlo [N][K] bf16.
// ---------------------------------------------------------------------------
__global__ __launch_bounds__(256)
void wsplitT_kernel(const float* __restrict__ W, unsigned short* __restrict__ Thi,
                    unsigned short* __restrict__ Tlo)
{
    __shared__ float tile[32][33];
    const int tx = threadIdx.x & 31, ty = threadIdx.x >> 5;
    const int n0 = blockIdx.x * 32, k0 = blockIdx.y * 32;
    #pragma unroll
    for (int i = 0; i < 4; ++i) {
        const int kk = ty + i * 8;
        tile[kk][tx] = W[(size_t)(k0 + kk) * 1280 + n0 + tx];
    }
    __syncthreads();
    #pragma unroll
    for (int i = 0; i < 4; ++i) {
        const int nn = ty + i * 8;
        const float v = tile[tx][nn];               // = W[k0+tx][n0+nn]
        const unsigned short h = f2bf(v);
        const size_t oi = (size_t)(n0 + nn) * 1280 + k0 + tx;
        Thi[oi] = h;
        Tlo[oi] = f2bf(v - bf2f(h));
    }
}

// ---------------------------------------------------------------------------
// Injection + fp32->bf16 for the O-projection A operand:
// a = ctx*(1-8*cf) + cf*csum, cf = posm[row]*CINJ_.
// ---------------------------------------------------------------------------
__global__ __launch_bounds__(256)
void inject_convert_kernel(const float* __restrict__ ctx, const float* __restrict__ csum,
                           const float* __restrict__ posm, unsigned short* __restrict__ outb)
{
    const size_t i4 = (size_t)blockIdx.x * 256 + threadIdx.x;   // float4 index
    const int row = (int)(i4 / 320);
    const int c4  = (int)(i4 % 320);
    const float cf = posm[row] * CINJ_;
    const float am = 1.0f - 8.0f * cf;
    const float4 c  = ((const float4*)ctx)[i4];
    const float4 cs = ((const float4*)csum)[(size_t)(row & (S_ - 1)) * 320 + c4];
    ushort4 h;
    h.x = f2bf(c.x * am + cf * cs.x);
    h.y = f2bf(c.y * am + cf * cs.y);
    h.z = f2bf(c.z * am + cf * cs.z);
    h.w = f2bf(c.w * am + cf * cs.w);
    ((ushort4*)outb)[i4] = h;
}

// ---------------------------------------------------------------------------
// MFMA GEMM: C[M x 1280] = A[M x K] * B[K x 1280], A and B^T given in bf16.
// 128x128 tile, BK=32, 4 waves (2x2 of 64x64), 16x16x32 bf16 MFMA.
// SPLIT: acc += Ah*Bh + Ah*Bl + Al*Bh (fp32-ish accuracy).
// Grid: 1-D, 2560 blocks, L2-panel swizzle: 8 panels x (32 m-tiles x 10
// n-tiles), m fastest. Working set/panel = 21 MB A + streamed B slab; B is
// re-fetched from HBM only once per panel (8x6.5 MB) instead of once per
// 10-block group (256x6.5 MB) — kills the round-2 2.0 GB FETCH.
// ---------------------------------------------------------------------------
__device__ inline void stage_tile(const unsigned short* __restrict__ gsrc,
                                  unsigned short* lds, int tid, int ldK,
                                  int row0, int k0)
{
    #pragma unroll
    for (int c0 = 0; c0 < 512; c0 += 256) {
        const int c = c0 + tid;
        const unsigned short* gp = gsrc + (size_t)(row0 + (c >> 2)) * ldK + k0 + (c & 3) * 8;
        __builtin_amdgcn_global_load_lds((const AS_G void*)gp, (AS_L void*)(lds + (size_t)c * 8),
                                         16, 0, 0);
    }
}

template<bool SPLIT, bool FUSE_OUT>
__global__ __launch_bounds__(256)
void mfma_gemm_kernel(const unsigned short* __restrict__ Ahi, const unsigned short* __restrict__ Alo,
                      const unsigned short* __restrict__ BhiT, const unsigned short* __restrict__ BloT,
                      float* __restrict__ Cout, int K,
                      const float* __restrict__ bias, const float* __restrict__ resid)
{
    __shared__ unsigned short sAhi[128 * 32];
    __shared__ unsigned short sBhi[128 * 32];
    __shared__ unsigned short sAlo[SPLIT ? 128 * 32 : 8];
    __shared__ unsigned short sBlo[SPLIT ? 128 * 32 : 8];

    const int tid  = threadIdx.x;
    const int lane = tid & 63;
    const int wave = tid >> 6;
    const int quad = lane >> 4;
    const int lrow = lane & 15;
    const int wm = (wave & 1) * 64;
    const int wn = (wave >> 1) * 64;

    // L2 panel swizzle: panel = 32 m-tiles; within panel m fastest, n slow.
    const int bid = blockIdx.x;
    const int panel = bid / 320;
    const int r = bid % 320;
    const int n0 = (r >> 5) * 128;
    const int m0 = (panel * 32 + (r & 31)) * 128;

    f32x4 acc[4][4] = {};

    for (int k0 = 0; k0 < K; k0 += 32) {
        __syncthreads();
        stage_tile(Ahi,  sAhi, tid, K, m0, k0);
        stage_tile(BhiT, sBhi, tid, K, n0, k0);
        if constexpr (SPLIT) {
            stage_tile(Alo,  sAlo, tid, K, m0, k0);
            stage_tile(BloT, sBlo, tid, K, n0, k0);
        }
        __syncthreads();

        bf16x8 ah[4], bh[4];
        #pragma unroll
        for (int i = 0; i < 4; ++i) {
            ah[i] = *(const bf16x8*)(sAhi + (wm + i * 16 + lrow) * 32 + quad * 8);
            bh[i] = *(const bf16x8*)(sBhi + (wn + i * 16 + lrow) * 32 + quad * 8);
        }
        if constexpr (SPLIT) {
            bf16x8 al[4], bl[4];
            #pragma unroll
            for (int i = 0; i < 4; ++i) {
                al[i] = *(const bf16x8*)(sAlo + (wm + i * 16 + lrow) * 32 + quad * 8);
                bl[i] = *(const bf16x8*)(sBlo + (wn + i * 16 + lrow) * 32 + quad * 8);
            }
            #pragma unroll
            for (int mt = 0; mt < 4; ++mt)
                #pragma unroll
                for (int nt = 0; nt < 4; ++nt) {
                    acc[mt][nt] = __builtin_amdgcn_mfma_f32_16x16x32_bf16(ah[mt], bh[nt], acc[mt][nt], 0, 0, 0);
                    acc[mt][nt] = __builtin_amdgcn_mfma_f32_16x16x32_bf16(ah[mt], bl[nt], acc[mt][nt], 0, 0, 0);
                    acc[mt][nt] = __builtin_amdgcn_mfma_f32_16x16x32_bf16(al[mt], bh[nt], acc[mt][nt], 0, 0, 0);
                }
        } else {
            #pragma unroll
            for (int mt = 0; mt < 4; ++mt)
                #pragma unroll
                for (int nt = 0; nt < 4; ++nt)
                    acc[mt][nt] = __builtin_amdgcn_mfma_f32_16x16x32_bf16(ah[mt], bh[nt], acc[mt][nt], 0, 0, 0);
        }
    }

    // Epilogue: C/D layout col = lane&15, row = quad*4 + reg (m89/m91-verified)
    #pragma unroll
    for (int mt = 0; mt < 4; ++mt) {
        #pragma unroll
        for (int nt = 0; nt < 4; ++nt) {
            const int col = n0 + wn + nt * 16 + lrow;
            #pragma unroll
            for (int r2 = 0; r2 < 4; ++r2) {
                const int row = m0 + wm + mt * 16 + quad * 4 + r2;
                float v = acc[mt][nt][r2];
                if constexpr (FUSE_OUT)
                    v += bias[col] + resid[(size_t)row * 1280 + col];
                Cout[(size_t)row * 1280 + col] = v;
            }
        }
    }
}

// ---------------------------------------------------------------------------
// fp32 GEMM, 64x64 tile, BK=16, 256 threads, 4x4 micro-tile. For K/V
// projections (M=616, K=2048, N=1280) — stays fp32 (feeds scoring path).
// ---------------------------------------------------------------------------
__global__ __launch_bounds__(256)
void gemm64_kernel(const float* __restrict__ A,
                   const float* __restrict__ B0, const float* __restrict__ B1,
                   float* __restrict__ C0, float* __restrict__ C1,
                   int M, int N, int K)
{
    const float* Bm = blockIdx.z ? B1 : B0;
    float* Cout = blockIdx.z ? C1 : C0;
    __shared__ float As[16][64];
    __shared__ float Bs[16][64];
    const int tid = threadIdx.x;
    const int n0 = blockIdx.x * 64;
    const int m0 = blockIdx.y * 64;
    const int tx = tid & 15, ty = tid >> 4;
    const int ar = tid >> 2;
    const int ak = (tid & 3) << 2;
    const int bk = tid >> 4;
    const int bn = (tid & 15) << 2;

    float acc[4][4] = {};
    const int arow = m0 + ar;
    const bool avalid = arow < M;
    const float* Ap = A + (size_t)arow * K + ak;
    const float* Bp = Bm + (size_t)bk * N + n0 + bn;

    for (int k0 = 0; k0 < K; k0 += 16) {
        const float4 a = avalid ? *(const float4*)(Ap + k0) : make_float4(0.f,0.f,0.f,0.f);
        const float4 b = *(const float4*)(Bp + (size_t)k0 * N);
        __syncthreads();
        As[ak+0][ar] = a.x; As[ak+1][ar] = a.y; As[ak+2][ar] = a.z; As[ak+3][ar] = a.w;
        *(float4*)&Bs[bk][bn] = b;
        __syncthreads();
        #pragma unroll
        for (int kk = 0; kk < 16; ++kk) {
            const float4 av = *(const float4*)&As[kk][ty*4];
            const float4 bv = *(const float4*)&Bs[kk][tx*4];
            const float arr[4] = {av.x, av.y, av.z, av.w};
            const float brr[4] = {bv.x, bv.y, bv.z, bv.w};
            #pragma unroll
            for (int r = 0; r < 4; ++r)
                #pragma unroll
                for (int c = 0; c < 4; ++c)
                    acc[r][c] = fmaf(arr[r], brr[c], acc[r][c]);
        }
    }
    #pragma unroll
    for (int r = 0; r < 4; ++r) {
        const int row = m0 + ty * 4 + r;
        if (row < M) {
            const float4 cv = make_float4(acc[r][0], acc[r][1], acc[r][2], acc[r][3]);
            *(float4*)(Cout + (size_t)row * N + n0 + tx * 4) = cv;
        }
    }
}

// ---------------------------------------------------------------------------
// helpers
// ---------------------------------------------------------------------------
__device__ inline float dot64v(const float4* __restrict__ qr, const float* __restrict__ kr)
{
    const float4* k4 = (const float4*)kr;
    float d0 = 0.f, d1 = 0.f, d2 = 0.f, d3 = 0.f;
    #pragma unroll
    for (int i = 0; i < 16; ++i) {
        const float4 kv = k4[i];
        const float4 qv = qr[i];
        d0 = fmaf(qv.x, kv.x, d0);
        d1 = fmaf(qv.y, kv.y, d1);
        d2 = fmaf(qv.z, kv.z, d2);
        d3 = fmaf(qv.w, kv.w, d3);
    }
    return (d0 + d1) + (d2 + d3);
}

__device__ inline bool first_pair(float va, int ia, float vb, int ib)
{
    return (va > vb) || (va == vb && ia < ib);
}

// descending by (value, then index asc) — matches lax.top_k tie-break
__device__ inline void bitonic_desc(float* vals, int* idxs, int n, int tid, int nt)
{
    for (int k = 2; k <= n; k <<= 1) {
        for (int j = k >> 1; j > 0; j >>= 1) {
            __syncthreads();
            for (int i = tid; i < n; i += nt) {
                const int l = i ^ j;
                if (l > i) {
                    const float vi = vals[i], vl = vals[l];
                    const int   ii = idxs[i], il = idxs[l];
                    const bool up = (i & k) == 0;
                    const bool sw = up ? first_pair(vl, il, vi, ii)
                                       : first_pair(vi, ii, vl, il);
                    if (sw) { vals[i] = vl; vals[l] = vi; idxs[i] = il; idxs[l] = ii; }
                }
            }
        }
    }
    __syncthreads();
}

// ---------------------------------------------------------------------------
// Pass A: first attention, accumulate sum of probs over (h,s) per (b,t).
// Grid: 2560 blocks = b(8) x h(20) x s-chunk(16); 256 threads = 256 s values.
// ---------------------------------------------------------------------------
__global__ __launch_bounds__(256)
void pass_a_kernel(const float* __restrict__ q, const float* __restrict__ kbuf,
                   float* __restrict__ tokp)
{
    __shared__ float sk[T_ * D_];
    __shared__ float wsum[4][T_];
    const int g = blockIdx.x;
    const int b = g / 320;
    const int rem = g % 320;
    const int h = rem >> 4;
    const int chunk = rem & 15;
    const int tid = threadIdx.x;

    for (int i = tid; i < T_ * D_; i += 256) {
        const int t = i >> 6, d = i & 63;
        sk[i] = kbuf[(size_t)b * T_ * HD_ + (size_t)t * HD_ + h * D_ + d];
    }
    __syncthreads();

    const int s = chunk * 256 + tid;
    const float* qp = q + (size_t)(b * S_ + s) * HD_ + h * D_;
    float4 qr[16];
    #pragma unroll
    for (int i = 0; i < 16; ++i) qr[i] = *(const float4*)(qp + 4 * i);

    float mx = -1e30f, L = 0.f;
    for (int t = 0; t < T_; ++t) {
        const float l = dot64v(qr, sk + t * D_) * SCALE_;
        const float nm = fmaxf(mx, l);
        L = L * __expf(mx - nm) + __expf(l - nm);
        mx = nm;
    }
    const float invL = 1.0f / L;
    const int wid = tid >> 6;
    const int lane = tid & 63;
    for (int t = 0; t < T_; ++t) {
        const float l = dot64v(qr, sk + t * D_) * SCALE_;
        float p = __expf(l - mx) * invL;
        #pragma unroll
        for (int off = 32; off > 0; off >>= 1) p += __shfl_xor(p, off, 64);
        if (lane == 0) wsum[wid][t] = p;
    }
    __syncthreads();
    for (int t = tid; t < T_; t += 256)
        tokp[(size_t)g * T_ + t] = (wsum[0][t] + wsum[1][t]) + (wsum[2][t] + wsum[3][t]);
}

// ---------------------------------------------------------------------------
// Top-k over 77 token scores per batch -> tok_mask. 8 blocks x 128 threads.
// ---------------------------------------------------------------------------
__global__ __launch_bounds__(128)
void topk_tok_kernel(const float* __restrict__ tokp, float* __restrict__ tokm)
{
    __shared__ float vals[128];
    __shared__ int idxs[128];
    const int b = blockIdx.x, tid = threadIdx.x;
    float v = -1e30f;
    if (tid < T_) {
        float sm = 0.f;
        for (int j = 0; j < 320; ++j) sm += tokp[(size_t)(b * 320 + j) * T_ + tid];
        v = sm;
    }
    vals[tid] = v; idxs[tid] = tid;
    bitonic_desc(vals, idxs, 128, tid, 128);
    if (tid < T_) tokm[b * T_ + tid] = 0.f;
    __syncthreads();
    if (tid < KTOK_) tokm[b * T_ + idxs[tid]] = 1.0f;
}

// ---------------------------------------------------------------------------
// K/V cross-frame mixing: kd = k2-k (delta), v2 = mixed v. 385 blocks x 256.
// ---------------------------------------------------------------------------
__global__ __launch_bounds__(256)
void mix_kernel(const float* __restrict__ kbuf, const float* __restrict__ vbuf,
                const float* __restrict__ tokm,
                float* __restrict__ kd, float* __restrict__ v2)
{
    const int i = blockIdx.x * 256 + threadIdx.x;   // < 77*1280 = 98560
    const int t = i / HD_;
    float ks = 0.f, vs = 0.f;
    #pragma unroll
    for (int b = 0; b < B_; ++b) {
        ks += kbuf[(size_t)b * T_ * HD_ + i];
        vs += vbuf[(size_t)b * T_ * HD_ + i];
    }
    #pragma unroll
    for (int b = 0; b < B_; ++b) {
        const size_t gi = (size_t)b * T_ * HD_ + i;
        const float msk = tokm[b * T_ + t];
        const float kx = kbuf[gi], vx = vbuf[gi];
        kd[gi] = CMIX_ * msk * ((ks - 8.f * kx) * (1.0f / 7.0f));
        v2[gi] = vx + CMIX_ * msk * ((vs - 8.f * vx) * (1.0f / 7.0f));
    }
}

// ---------------------------------------------------------------------------
// Fused pass B+C: per (b,h,s) row, compute masked prob-mass from ORIGINAL k
// (pos score partial) and second-attention context from k2=k+kd, v2.
// ---------------------------------------------------------------------------
__global__ __launch_bounds__(256)
void pass_bc_kernel(const float* __restrict__ q, const float* __restrict__ kbuf,
                    const float* __restrict__ kd, const float* __restrict__ v2,
                    const float* __restrict__ tokm,
                    float* __restrict__ posp, float* __restrict__ ctx)
{
    __shared__ float sk[T_ * D_];
    __shared__ float sd[T_ * D_];
    __shared__ float sv[T_ * D_];
    __shared__ int smask[T_];
    const int g = blockIdx.x;
    const int b = g / 320;
    const int rem = g % 320;
    const int h = rem >> 4;
    const int chunk = rem & 15;
    const int tid = threadIdx.x;

    for (int i = tid; i < T_ * D_; i += 256) {
        const int t = i >> 6, d = i & 63;
        const size_t gi = (size_t)b * T_ * HD_ + (size_t)t * HD_ + h * D_ + d;
        sk[i] = kbuf[gi];
        sd[i] = kd[gi];
        sv[i] = v2[gi];
    }
    for (int t = tid; t < T_; t += 256) smask[t] = (tokm[b * T_ + t] > 0.5f) ? 1 : 0;
    __syncthreads();

    const int s = chunk * 256 + tid;
    const float* qp = q + (size_t)(b * S_ + s) * HD_ + h * D_;
    float4 qr[16];
    #pragma unroll
    for (int i = 0; i < 16; ++i) qr[i] = *(const float4*)(qp + 4 * i);

    float m1 = -1e30f, L1 = 0.f, Sm = 0.f;
    float m2 = -1e30f, L2 = 0.f;
    for (int t = 0; t < T_; ++t) {
        const float l1 = dot64v(qr, sk + t * D_) * SCALE_;
        float l2 = l1;
        const int msk = smask[t];
        if (msk) l2 = l1 + dot64v(qr, sd + t * D_) * SCALE_;
        const float nm1 = fmaxf(m1, l1);
        const float sc1 = __expf(m1 - nm1);
        const float e1  = __expf(l1 - nm1);
        L1 = L1 * sc1 + e1;
        Sm = Sm * sc1 + (msk ? e1 : 0.f);
        m1 = nm1;
        const float nm2 = fmaxf(m2, l2);
        L2 = L2 * __expf(m2 - nm2) + __expf(l2 - nm2);
        m2 = nm2;
    }
    posp[(size_t)(b * H_ + h) * S_ + s] = Sm / L1;

    const float invL2 = 1.0f / L2;
    float4 cacc[16] = {};
    for (int t = 0; t < T_; ++t) {
        float l2 = dot64v(qr, sk + t * D_) * SCALE_;
        if (smask[t]) l2 += dot64v(qr, sd + t * D_) * SCALE_;
        const float p = __expf(l2 - m2) * invL2;
        const float4* vv = (const float4*)(sv + t * D_);
        #pragma unroll
        for (int i = 0; i < 16; ++i) {
            const float4 vx = vv[i];
            cacc[i].x = fmaf(p, vx.x, cacc[i].x);
            cacc[i].y = fmaf(p, vx.y, cacc[i].y);
            cacc[i].z = fmaf(p, vx.z, cacc[i].z);
            cacc[i].w = fmaf(p, vx.w, cacc[i].w);
        }
    }
    float* cp = ctx + (size_t)(b * S_ + s) * HD_ + h * D_;
    #pragma unroll
    for (int i = 0; i < 16; ++i) *(float4*)(cp + 4 * i) = cacc[i];
}

// ---------------------------------------------------------------------------
// Top-k over 4096 position scores per batch -> pos_mask. 8 blocks x 1024.
// ---------------------------------------------------------------------------
__global__ __launch_bounds__(1024)
void topk_pos_kernel(const float* __restrict__ posp, float* __restrict__ posm)
{
    __shared__ float vals[S_];
    __shared__ int idxs[S_];
    const int b = blockIdx.x, tid = threadIdx.x;
    for (int s = tid; s < S_; s += 1024) {
        float sm = 0.f;
        for (int h = 0; h < H_; ++h) sm += posp[(size_t)(b * H_ + h) * S_ + s];
        vals[s] = sm; idxs[s] = s;
    }
    bitonic_desc(vals, idxs, S_, tid, 1024);
    for (int s = tid; s < S_; s += 1024) posm[b * S_ + s] = 0.f;
    __syncthreads();
    for (int i = tid; i < KPOS_; i += 1024) posm[b * S_ + idxs[i]] = 1.0f;
}

// ---------------------------------------------------------------------------
// Batch-sum of context over b: csum[s,hd] = sum_b ctx[b,s,hd]. float4 lanes.
// ---------------------------------------------------------------------------
__global__ __launch_bounds__(256)
void ctxsum_kernel(const float* __restrict__ ctx, float* __restrict__ csum)
{
    const size_t i = (size_t)blockIdx.x * 256 + threadIdx.x;  // float4 index
    const float4* c = (const float4*)ctx;
    float4 a = c[i];
    #pragma unroll
    for (int b = 1; b < B_; ++b) {
        const float4 x = c[(size_t)b * (S_ * HD_ / 4) + i];
        a.x += x.x; a.y += x.y; a.z += x.z; a.w += x.w;
    }
    ((float4*)csum)[i] = a;
}

// ---------------------------------------------------------------------------
extern "C" void kernel_launch(void* const* d_in, const int* in_sizes, int n_in,
                              void* d_out, int out_size, void* d_ws, size_t ws_size,
                              hipStream_t stream)
{
    const float* hidden = (const float*)d_in[0];
    const float* enc    = (const float*)d_in[1];
    const float* Wq     = (const float*)d_in[2];
    const float* Wk     = (const float*)d_in[3];
    const float* Wv     = (const float*)d_in[4];
    const float* Wo     = (const float*)d_in[5];
    const float* bo     = (const float*)d_in[6];
    float* out = (float*)d_out;

    char* w = (char*)d_ws;
    float* q    = (float*)w; w += (size_t)M1_ * HD_ * 4;
    float* ctx  = (float*)w; w += (size_t)M1_ * HD_ * 4;
    float* kbuf = (float*)w; w += (size_t)B_ * T_ * HD_ * 4;
    float* vbuf = (float*)w; w += (size_t)B_ * T_ * HD_ * 4;
    float* kd   = (float*)w; w += (size_t)B_ * T_ * HD_ * 4;
    float* v2   = (float*)w; w += (size_t)B_ * T_ * HD_ * 4;
    float* csum = (float*)w; w += (size_t)S_ * HD_ * 4;
    float* tokp = (float*)w; w += (size_t)2560 * T_ * 4;
    float* posp = (float*)w; w += (size_t)B_ * H_ * S_ * 4;
    float* tokm = (float*)w; w += (size_t)B_ * T_ * 4;
    float* posm = (float*)w; w += (size_t)B_ * S_ * 4;
    unsigned short* Ahi   = (unsigned short*)w; w += (size_t)M1_ * HD_ * 2;
    unsigned short* Alo   = (unsigned short*)w; w += (size_t)M1_ * HD_ * 2;
    unsigned short* ctxb  = (unsigned short*)w; w += (size_t)M1_ * HD_ * 2;
    unsigned short* WqhiT = (unsigned short*)w; w += (size_t)C_ * HD_ * 2;
    unsigned short* WqloT = (unsigned short*)w; w += (size_t)C_ * HD_ * 2;
    unsigned short* WohiT = (unsigned short*)w; w += (size_t)HD_ * C_ * 2;
    unsigned short* WoloT = (unsigned short*)w; w += (size_t)HD_ * C_ * 2;
    (void)ws_size; (void)in_sizes; (void)n_in; (void)out_size;

    // 1. Split hidden -> bf16 hi/lo; weights -> transposed bf16 hi/lo
    split_convert_kernel<<<M1_ * HD_ / 4 / 256, 256, 0, stream>>>(hidden, Ahi, Alo);
    wsplitT_kernel<<<dim3(40, 40), 256, 0, stream>>>(Wq, WqhiT, WqloT);
    wsplitT_kernel<<<dim3(40, 40), 256, 0, stream>>>(Wo, WohiT, WoloT);
    // 2. Q projection: split-bf16 MFMA (3 products ~ fp32 accuracy)
    mfma_gemm_kernel<true, false><<<2560, 256, 0, stream>>>(
        Ahi, Alo, WqhiT, WqloT, q, C_, nullptr, nullptr);
    // 3. K and V projections (fp32 — feeds scoring logits)
    gemm64_kernel<<<dim3(20, 10, 2), 256, 0, stream>>>(
        enc, Wk, Wv, kbuf, vbuf, MKV_, HD_, CENC_);
    // 4. First attention -> token-score partials
    pass_a_kernel<<<2560, 256, 0, stream>>>(q, kbuf, tokp);
    // 5. Token top-k mask
    topk_tok_kernel<<<8, 128, 0, stream>>>(tokp, tokm);
    // 6. Cross-frame K/V mixing
    mix_kernel<<<385, 256, 0, stream>>>(kbuf, vbuf, tokm, kd, v2);
    // 7. Fused pass B (pos scores) + pass C (second attention context)
    pass_bc_kernel<<<2560, 256, 0, stream>>>(q, kbuf, kd, v2, tokm, posp, ctx);
    // 8. Position top-k mask
    topk_pos_kernel<<<8, 1024, 0, stream>>>(posp, posm);
    // 9. Batch-sum of context for mean-of-others injection
    ctxsum_kernel<<<S_ * HD_ / 4 / 256, 256, 0, stream>>>(ctx, csum);
    // 10. Injection + bf16 convert of context (A operand of O-proj)
    inject_convert_kernel<<<M1_ * HD_ / 4 / 256, 256, 0, stream>>>(ctx, csum, posm, ctxb);
    // 11. O projection: plain bf16 MFMA + bias + residual epilogue
    mfma_gemm_kernel<false, true><<<2560, 256, 0, stream>>>(
        ctxb, nullptr, WohiT, nullptr, out, HD_, bo, hidden);
}